// Round 1
// baseline (95.782 us; speedup 1.0000x reference)
//
#include <hip/hip_runtime.h>

// TensorTrainEmbedding: B=131072 elements, each:
//   v0 = end_core[h2] (4x16), core = cores[h1] (4x16x16), start = start_core[h0] (4x16)
//   t[d][s][e] = sum_r core[d][s][r]*v0[e][r]
//   out[d'*16+d*4+e] = sum_s start[d'][s]*t[d][s][e]
// One wave per element; memory-bound gather (~4.8 KiB read / 256 B write per elem).

#define WPB 4           // waves per block (block = 256 threads)
#define T_STRIDE 20     // LDS stride for t: (d*4+e)*20+s -> <=2-way bank alias (free)

__global__ __launch_bounds__(256) void tt_embed_kernel(
    const int* __restrict__ hs,
    const float* __restrict__ start_core,
    const float* __restrict__ end_core,
    const float* __restrict__ cores,
    float* __restrict__ out,
    int B)
{
    __shared__ __align__(16) float lds_t[WPB][16 * T_STRIDE];

    const int tid  = threadIdx.x;
    const int wave = tid >> 6;
    const int lane = tid & 63;

    int b = blockIdx.x * WPB + wave;
    b = __builtin_amdgcn_readfirstlane(b);   // wave-uniform -> scalar path
    const bool active = (b < B);

    float st[16];   // start row for phase 2 (per-lane d' = lane>>4)
    float t[4];

    if (active) {
        // indices are wave-uniform -> s_load
        const int h0 = __builtin_amdgcn_readfirstlane(hs[3 * b + 0]);
        const int h1 = __builtin_amdgcn_readfirstlane(hs[3 * b + 1]);
        const int h2 = __builtin_amdgcn_readfirstlane(hs[3 * b + 2]);

        // ---- phase 1: lane = (d = lane>>4, s = lane&15) owns one core row ----
        // core row: 16 contiguous floats at flat offset lane*16 within the 4 KiB slice
        const float* crp = cores + ((size_t)h1 << 10) + lane * 16;
        float c[16];
        *(float4*)(c + 0)  = *(const float4*)(crp + 0);
        *(float4*)(c + 4)  = *(const float4*)(crp + 4);
        *(float4*)(c + 8)  = *(const float4*)(crp + 8);
        *(float4*)(c + 12) = *(const float4*)(crp + 12);

        // start row (phase 2 operand): d' = lane>>4, 16 contiguous floats
        const float* stp = start_core + ((size_t)h0 << 6) + ((lane >> 4) << 4);
        *(float4*)(st + 0)  = *(const float4*)(stp + 0);
        *(float4*)(st + 4)  = *(const float4*)(stp + 4);
        *(float4*)(st + 8)  = *(const float4*)(stp + 8);
        *(float4*)(st + 12) = *(const float4*)(stp + 12);

        // v0 = end_core[h2]: 64 floats, wave-uniform -> SGPR broadcast
        const float* v0p = end_core + ((size_t)h2 << 6);
        #pragma unroll
        for (int e = 0; e < 4; ++e) {
            const float* ve = v0p + e * 16;
            float a = c[0] * ve[0];
            #pragma unroll
            for (int r = 1; r < 16; ++r)
                a = fmaf(c[r], ve[r], a);
            t[e] = a;
        }

        // write t to LDS: index (d*4+e)*T_STRIDE + s
        const int d = lane >> 4;
        const int s = lane & 15;
        #pragma unroll
        for (int e = 0; e < 4; ++e)
            lds_t[wave][(d * 4 + e) * T_STRIDE + s] = t[e];
    }

    __syncthreads();

    if (active) {
        // ---- phase 2: lane = output index o = d'*16 + (d*4+e); de = lane&15 ----
        const float* tp = &lds_t[wave][(lane & 15) * T_STRIDE];
        float tt[16];
        *(float4*)(tt + 0)  = *(const float4*)(tp + 0);
        *(float4*)(tt + 4)  = *(const float4*)(tp + 4);
        *(float4*)(tt + 8)  = *(const float4*)(tp + 8);
        *(float4*)(tt + 12) = *(const float4*)(tp + 12);

        float a = st[0] * tt[0];
        #pragma unroll
        for (int k = 1; k < 16; ++k)
            a = fmaf(st[k], tt[k], a);

        out[((size_t)b << 6) + lane] = a;   // wave writes 256 B contiguous
    }
}

extern "C" void kernel_launch(void* const* d_in, const int* in_sizes, int n_in,
                              void* d_out, int out_size, void* d_ws, size_t ws_size,
                              hipStream_t stream) {
    const int*   hs         = (const int*)d_in[0];
    const float* start_core = (const float*)d_in[1];
    const float* end_core   = (const float*)d_in[2];
    const float* cores      = (const float*)d_in[3];
    float* out = (float*)d_out;

    const int B = in_sizes[0] / 3;                 // hs is (B, 3)
    const int grid = (B + WPB - 1) / WPB;

    hipLaunchKernelGGL(tt_embed_kernel, dim3(grid), dim3(256), 0, stream,
                       hs, start_core, end_core, cores, out, B);
}